// Round 1
// baseline (338.551 us; speedup 1.0000x reference)
//
#include <hip/hip_runtime.h>

// Composite loss: 0.16*MSE + 0.84*(1-SSIM), 16x3x512x512 f32, win=11 sigma=1.5
// One fused tile kernel (conv+pointwise+reduce) + tiny finalize kernel.

#define TW 64          // output tile width
#define TH 16          // output tile height
#define IW 74          // TW+10 input halo width
#define IH 26          // TH+10 input halo height
#define SXW 76         // padded LDS stride for staged inputs (float)
#define SH4W 65        // padded LDS stride for float4 conv plane
#define SH1W 67        // padded LDS stride for float conv plane

__global__ __launch_bounds__(256) void ssim_main(
    const float* __restrict__ pred, const float* __restrict__ targ,
    float* __restrict__ accum)
{
    __shared__ float  sX[IH * SXW];
    __shared__ float  sY[IH * SXW];
    __shared__ float4 sH4[IH * SH4W];   // (cx, cy, cxx, cyy)
    __shared__ float  sH1[IH * SH1W];   // cxy
    __shared__ float  red[8];           // 4 waves x {mse, ssim}

    const int tid = threadIdx.x;
    const int b   = blockIdx.x;
    const int img = b >> 8;             // 256 tiles per (batch,channel) plane
    const int t   = b & 255;
    const int ox0 = (t & 7) * TW;       // 8 tiles across
    const int oy0 = (t >> 3) * TH;      // 32 tiles down
    const float* P = pred + (size_t)img * (512 * 512);
    const float* T = targ + (size_t)img * (512 * 512);

    // Gaussian window, computed exactly like the reference (normalized exp)
    float wv[11];
    {
        float s = 0.f;
        #pragma unroll
        for (int i = 0; i < 11; ++i) {
            float d = (float)i - 5.0f;
            wv[i] = expf(-(d * d) / 4.5f);
            s += wv[i];
        }
        float inv = 1.0f / s;
        #pragma unroll
        for (int i = 0; i < 11; ++i) wv[i] *= inv;
    }

    // ---- phase 0: load + clip + stage; MSE over this block's disjoint core
    float mse_acc = 0.f;
    for (int i = tid; i < IH * IW; i += 256) {
        int r = i / IW;
        int c = i - r * IW;
        int gx = ox0 + c; if (gx > 511) gx = 511;   // clamped pixels feed only invalid outputs
        int gy = oy0 + r; if (gy > 511) gy = 511;
        float x = P[gy * 512 + gx];
        float y = T[gy * 512 + gx];
        x = fminf(fmaxf(x, 0.f), 1.f);
        y = fminf(fmaxf(y, 0.f), 1.f);
        sX[r * SXW + c] = x;
        sY[r * SXW + c] = y;
        if (c < TW && r < TH) { float d = x - y; mse_acc += d * d; }
    }
    __syncthreads();

    // ---- phase 1: horizontal 11-tap conv of 5 planes; 26 rows x 8 col-groups
    if (tid < IH * 8) {
        int r  = tid >> 3;
        int cb = (tid & 7) * 8;
        const float* xrow = &sX[r * SXW + cb];
        const float* yrow = &sY[r * SXW + cb];
        float cx[8], cy[8], cxx[8], cyy[8], cxy[8];
        #pragma unroll
        for (int j = 0; j < 8; ++j) { cx[j] = cy[j] = cxx[j] = cyy[j] = cxy[j] = 0.f; }
        #pragma unroll
        for (int i = 0; i < 18; ++i) {
            float x = xrow[i], y = yrow[i];
            float xx = x * x, yy = y * y, xy = x * y;
            #pragma unroll
            for (int j = 0; j < 8; ++j) {
                int k = i - j;                       // compile-time after unroll
                if (k >= 0 && k <= 10) {
                    float w = wv[k];
                    cx[j]  += w * x;  cy[j]  += w * y;
                    cxx[j] += w * xx; cyy[j] += w * yy; cxy[j] += w * xy;
                }
            }
        }
        #pragma unroll
        for (int j = 0; j < 8; ++j) {
            sH4[r * SH4W + cb + j] = make_float4(cx[j], cy[j], cxx[j], cyy[j]);
            sH1[r * SH1W + cb + j] = cxy[j];
        }
    }
    __syncthreads();

    // ---- phase 2: vertical 11-tap conv + SSIM map + accumulate
    float ssim_acc = 0.f;
    {
        const int tx = tid & 63;
        const int ty = tid >> 6;        // 0..3
        const int rb = ty * 4;          // output-row base (4 rows per thread)
        float acx[4], acy[4], acxx[4], acyy[4], acxy[4];
        #pragma unroll
        for (int j = 0; j < 4; ++j) { acx[j] = acy[j] = acxx[j] = acyy[j] = acxy[j] = 0.f; }
        #pragma unroll
        for (int i = 0; i < 14; ++i) {
            float4 h  = sH4[(rb + i) * SH4W + tx];
            float  h1 = sH1[(rb + i) * SH1W + tx];
            #pragma unroll
            for (int j = 0; j < 4; ++j) {
                int k = i - j;                       // compile-time after unroll
                if (k >= 0 && k <= 10) {
                    float w = wv[k];
                    acx[j]  += w * h.x; acy[j]  += w * h.y;
                    acxx[j] += w * h.z; acyy[j] += w * h.w;
                    acxy[j] += w * h1;
                }
            }
        }
        const float C1 = 1e-4f, C2 = 9e-4f;
        const int oxg = ox0 + tx;
        #pragma unroll
        for (int j = 0; j < 4; ++j) {
            int oyg = oy0 + rb + j;
            if (oxg < 502 && oyg < 502) {
                float mu1 = acx[j], mu2 = acy[j];
                float m11 = mu1 * mu1, m22 = mu2 * mu2, m12 = mu1 * mu2;
                float s1  = acxx[j] - m11;
                float s2  = acyy[j] - m22;
                float s12 = acxy[j] - m12;
                float num = (2.f * m12 + C1) * (2.f * s12 + C2);
                float den = (m11 + m22 + C1) * (s1 + s2 + C2);
                ssim_acc += num * __builtin_amdgcn_rcpf(den);
            }
        }
    }

    // ---- block reduction -> 2 atomics
    float vx = mse_acc, vy = ssim_acc;
    #pragma unroll
    for (int off = 32; off > 0; off >>= 1) {
        vx += __shfl_down(vx, off);
        vy += __shfl_down(vy, off);
    }
    const int wave = tid >> 6, lane = tid & 63;
    if (lane == 0) { red[wave * 2] = vx; red[wave * 2 + 1] = vy; }
    __syncthreads();
    if (tid == 0) {
        float ms = red[0] + red[2] + red[4] + red[6];
        float ss = red[1] + red[3] + red[5] + red[7];
        atomicAdd(&accum[0], ms);
        atomicAdd(&accum[1], ss);
    }
}

__global__ void ssim_finalize(const float* __restrict__ acc, float* __restrict__ out)
{
    // N_mse = 16*3*512*512 = 12582912 ; N_ssim = 16*3*502*502 = 12096192
    float mse  = acc[0] * (1.0f / 12582912.0f);
    float ssim = acc[1] * (1.0f / 12096192.0f);
    out[0] = 0.16f * mse + 0.84f * (1.0f - ssim);
}

extern "C" void kernel_launch(void* const* d_in, const int* in_sizes, int n_in,
                              void* d_out, int out_size, void* d_ws, size_t ws_size,
                              hipStream_t stream)
{
    const float* pred = (const float*)d_in[0];
    const float* targ = (const float*)d_in[1];
    float* ws = (float*)d_ws;

    hipMemsetAsync(ws, 0, 2 * sizeof(float), stream);
    // 48 planes * 8 x-tiles * 32 y-tiles = 12288 blocks
    ssim_main<<<12288, 256, 0, stream>>>(pred, targ, ws);
    ssim_finalize<<<1, 1, 0, stream>>>(ws, (float*)d_out);
}

// Round 2
// 173.565 us; speedup vs baseline: 1.9506x; 1.9506x over previous
//
#include <hip/hip_runtime.h>

// Composite loss: 0.16*MSE + 0.84*(1-SSIM), 16x3x512x512 f32, win=11 sigma=1.5
// Vertical-first streaming design:
//   block = full image width (512 cols) x OH=4 output rows
//   phase A: per-thread 2-col vertical conv of 5 planes (registers), -> LDS
//   phase B: per-thread 4-col x 2-row horizontal conv + SSIM map (b128 LDS reads)
// LDS = 5*4*512*4 = 40960 B exactly -> 4 blocks/CU.

#define OH   4
#define WROW 512   // LDS row stride in floats

__global__ __launch_bounds__(256, 4) void ssim_fused(
    const float* __restrict__ pred, const float* __restrict__ targ,
    float* __restrict__ accum)
{
    __shared__ float sV[5 * OH * WROW];   // 40960 B

    // Normalized 11-tap Gaussian (sigma=1.5), precomputed
    const float wv[11] = {
        0.00102838f, 0.00759876f, 0.03600078f, 0.10936070f, 0.21300554f,
        0.26601173f,
        0.21300554f, 0.10936070f, 0.03600078f, 0.00759876f, 0.00102838f };

    const int tid = threadIdx.x;
    // XCD-aware swizzle: 6144 blocks = 8 XCDs * 768 contiguous
    const int bid = ((int)blockIdx.x & 7) * 768 + ((int)blockIdx.x >> 3);
    const int img = bid >> 7;             // 48 planes
    const int oy0 = (bid & 127) * OH;     // 128 row-strips (covers MSE rows 0..511)
    const float* __restrict__ P = pred + (size_t)img * (512 * 512);
    const float* __restrict__ T = targ + (size_t)img * (512 * 512);

    // ---------------- phase A: vertical 11-tap conv, 2 cols/thread ----------
    const int c0 = tid * 2;

    float acc[5][OH][2];
    #pragma unroll
    for (int p = 0; p < 5; ++p)
        #pragma unroll
        for (int j = 0; j < OH; ++j) { acc[p][j][0] = 0.f; acc[p][j][1] = 0.f; }

    float mse_acc = 0.f;

    #pragma unroll
    for (int i = 0; i < OH + 10; ++i) {
        int gy = oy0 + i; if (gy > 511) gy = 511;   // clamped rows feed only masked outputs
        const float2 xv = *reinterpret_cast<const float2*>(P + gy * 512 + c0);
        const float2 yv = *reinterpret_cast<const float2*>(T + gy * 512 + c0);
        const float x0 = fminf(fmaxf(xv.x, 0.f), 1.f);
        const float x1 = fminf(fmaxf(xv.y, 0.f), 1.f);
        const float y0 = fminf(fmaxf(yv.x, 0.f), 1.f);
        const float y1 = fminf(fmaxf(yv.y, 0.f), 1.f);
        if (i < OH) {   // this block's disjoint MSE rows
            const float d0 = x0 - y0, d1 = x1 - y1;
            mse_acc += d0 * d0 + d1 * d1;
        }
        const float pr0[5] = { x0, y0, x0 * x0, y0 * y0, x0 * y0 };
        const float pr1[5] = { x1, y1, x1 * x1, y1 * y1, x1 * y1 };
        #pragma unroll
        for (int j = 0; j < OH; ++j) {
            const int k = i - j;
            if (k >= 0 && k <= 10) {
                const float w = wv[k];
                #pragma unroll
                for (int p = 0; p < 5; ++p) {
                    acc[p][j][0] = fmaf(w, pr0[p], acc[p][j][0]);
                    acc[p][j][1] = fmaf(w, pr1[p], acc[p][j][1]);
                }
            }
        }
    }

    #pragma unroll
    for (int p = 0; p < 5; ++p)
        #pragma unroll
        for (int j = 0; j < OH; ++j)
            *reinterpret_cast<float2*>(&sV[(p * OH + j) * WROW + c0]) =
                make_float2(acc[p][j][0], acc[p][j][1]);

    __syncthreads();

    // ---------------- phase B: horizontal 11-tap conv + SSIM map ------------
    const int g   = tid & 127;        // 4-col group
    const int rb  = (tid >> 7) * 2;   // rows rb, rb+1
    const int oc0 = g * 4;

    float ssim_acc = 0.f;
    const float C1 = 0.0001f, C2 = 0.0009f;

    #pragma unroll
    for (int rr = 0; rr < 2; ++rr) {
        const int r = rb + rr;
        float hc[5][4];
        #pragma unroll
        for (int p = 0; p < 5; ++p) {
            const float* base = &sV[(p * OH + r) * WROW];
            float win[16];
            #pragma unroll
            for (int q = 0; q < 4; ++q) {
                int cq = oc0 + q * 4;
                if (cq > 508) cq = 508;   // stay in-bounds; affects only masked cols
                const float4 v = *reinterpret_cast<const float4*>(base + cq);
                win[q * 4 + 0] = v.x; win[q * 4 + 1] = v.y;
                win[q * 4 + 2] = v.z; win[q * 4 + 3] = v.w;
            }
            #pragma unroll
            for (int cc = 0; cc < 4; ++cc) {
                float s = 0.f;
                #pragma unroll
                for (int dx = 0; dx < 11; ++dx)
                    s = fmaf(wv[dx], win[cc + dx], s);
                hc[p][cc] = s;
            }
        }
        const int oyg = oy0 + r;
        if (oyg < 502) {
            #pragma unroll
            for (int cc = 0; cc < 4; ++cc) {
                if (oc0 + cc < 502) {
                    const float mu1 = hc[0][cc], mu2 = hc[1][cc];
                    const float m11 = mu1 * mu1, m22 = mu2 * mu2, m12 = mu1 * mu2;
                    const float s1  = hc[2][cc] - m11;
                    const float s2  = hc[3][cc] - m22;
                    const float s12 = hc[4][cc] - m12;
                    const float num = (2.f * m12 + C1) * (2.f * s12 + C2);
                    const float den = (m11 + m22 + C1) * (s1 + s2 + C2);
                    ssim_acc += num * __builtin_amdgcn_rcpf(den);
                }
            }
        }
    }

    // ---------------- reduction: wave shfl -> LDS -> 2 atomics --------------
    float vx = mse_acc, vy = ssim_acc;
    #pragma unroll
    for (int off = 32; off > 0; off >>= 1) {
        vx += __shfl_down(vx, off);
        vy += __shfl_down(vy, off);
    }
    __syncthreads();                     // phase-B LDS reads done; reuse sV
    const int wave = tid >> 6;
    if ((tid & 63) == 0) { sV[wave * 2] = vx; sV[wave * 2 + 1] = vy; }
    __syncthreads();
    if (tid == 0) {
        atomicAdd(&accum[0], sV[0] + sV[2] + sV[4] + sV[6]);
        atomicAdd(&accum[1], sV[1] + sV[3] + sV[5] + sV[7]);
    }
}

__global__ void ssim_finalize(const float* __restrict__ acc, float* __restrict__ out)
{
    // N_mse = 16*3*512*512 = 12582912 ; N_ssim = 16*3*502*502 = 12096192
    const float mse  = acc[0] * (1.0f / 12582912.0f);
    const float ssim = acc[1] * (1.0f / 12096192.0f);
    out[0] = 0.16f * mse + 0.84f * (1.0f - ssim);
}

extern "C" void kernel_launch(void* const* d_in, const int* in_sizes, int n_in,
                              void* d_out, int out_size, void* d_ws, size_t ws_size,
                              hipStream_t stream)
{
    const float* pred = (const float*)d_in[0];
    const float* targ = (const float*)d_in[1];
    float* ws = (float*)d_ws;

    hipMemsetAsync(ws, 0, 2 * sizeof(float), stream);
    // 48 planes * 128 row-strips = 6144 blocks
    ssim_fused<<<6144, 256, 0, stream>>>(pred, targ, ws);
    ssim_finalize<<<1, 1, 0, stream>>>(ws, (float*)d_out);
}